// Round 9
// baseline (678.554 us; speedup 1.0000x reference)
//
#include <hip/hip_runtime.h>
#include <hip/hip_bf16.h>
#include <cstdint>

// ---------- bf16 helpers (raw ushort representation) ----------
__device__ __forceinline__ unsigned short f2b(float f) {
    union { float f; unsigned int i; } v; v.f = f;
    unsigned int i = v.i;
    unsigned int r = (i + 0x7FFFu + ((i >> 16) & 1u)) >> 16;   // RNE, finite inputs
    return (unsigned short)r;
}
__device__ __forceinline__ float b2f_lo(unsigned int p) {
    union { unsigned int i; float f; } v; v.i = p << 16; return v.f;
}
__device__ __forceinline__ float b2f_hi(unsigned int p) {
    union { unsigned int i; float f; } v; v.i = p & 0xFFFF0000u; return v.f;
}
__device__ __forceinline__ unsigned int pack2(float a, float b) {
    return (unsigned int)f2b(a) | ((unsigned int)f2b(b) << 16);
}

typedef __attribute__((__ext_vector_type__(8))) __bf16 bf16x8;
typedef __attribute__((__ext_vector_type__(4))) float  f32x4;

#define N_NODES 100000
#define N_EDGES 3200000
#define NBUCK   400        // coarse buckets
#define BSZ     250        // nodes per bucket (400*250 = 100000)
#define NSCAT   256        // scatter blocks
#define CHUNK   12500      // edges per scatter block (256*12500 = 3.2M)
#define CAP     10000      // LDS segment capacity (bucket avg 8000, +22 sigma)

// ---------- 1. per-block bucket histograms + totals ----------
__global__ void k_hist_pb(const int* __restrict__ src, const int* __restrict__ dst,
                          int* __restrict__ countsA, int* __restrict__ countsB,
                          int* __restrict__ gcntA, int* __restrict__ gcntB, int E) {
    __shared__ int hA[NBUCK], hB[NBUCK];
    int t = threadIdx.x, blk = blockIdx.x;
    for (int j = t; j < NBUCK; j += 256) { hA[j] = 0; hB[j] = 0; }
    __syncthreads();
    int lo = blk * CHUNK, hi = min(lo + CHUNK, E);
    for (int i = lo + t; i < hi; i += 256) {
        atomicAdd(&hA[dst[i] / BSZ], 1);
        atomicAdd(&hB[src[i] / BSZ], 1);
    }
    __syncthreads();
    for (int j = t; j < NBUCK; j += 256) {
        countsA[j * NSCAT + blk] = hA[j];
        countsB[j * NSCAT + blk] = hB[j];
        if (hA[j]) atomicAdd(&gcntA[j], hA[j]);
        if (hB[j]) atomicAdd(&gcntB[j], hB[j]);
    }
}

// ---------- 2. scan bucket totals -> bucket bases ----------
__global__ void k_scan_coarse(const int* __restrict__ gcntA, const int* __restrict__ gcntB,
                              int* __restrict__ gbaseA, int* __restrict__ gbaseB,
                              int* __restrict__ offsets) {
    __shared__ int pA[512], pB[512];
    int t = threadIdx.x;
    int vA = (t < NBUCK) ? gcntA[t] : 0;
    int vB = (t < NBUCK) ? gcntB[t] : 0;
    pA[t] = vA; pB[t] = vB;
    __syncthreads();
    for (int d = 1; d < 512; d <<= 1) {
        int a = (t >= d) ? pA[t - d] : 0;
        int b = (t >= d) ? pB[t - d] : 0;
        __syncthreads();
        pA[t] += a; pB[t] += b;
        __syncthreads();
    }
    if (t < NBUCK) { gbaseA[t] = pA[t] - vA; gbaseB[t] = pB[t] - vB; }
    if (t == 511) {
        gbaseA[NBUCK] = pA[511];
        gbaseB[NBUCK] = pB[511];
        offsets[N_NODES] = pA[511];   // == E
    }
}

// ---------- 3. deterministic per-block scatter bases ----------
// block < NBUCK handles bucket (A); block >= NBUCK handles bucket (B)
__global__ void k_blockbase(const int* __restrict__ countsA, const int* __restrict__ countsB,
                            const int* __restrict__ gbaseA, const int* __restrict__ gbaseB,
                            int* __restrict__ basesA, int* __restrict__ basesB) {
    __shared__ int pp[256];
    int t = threadIdx.x;
    bool isA = blockIdx.x < NBUCK;
    int bkt = isA ? blockIdx.x : blockIdx.x - NBUCK;
    const int* counts = isA ? countsA : countsB;
    const int* gbase  = isA ? gbaseA  : gbaseB;
    int*       bases  = isA ? basesA  : basesB;
    int v = counts[bkt * NSCAT + t];
    pp[t] = v;
    __syncthreads();
    for (int d = 1; d < 256; d <<= 1) {
        int a = (t >= d) ? pp[t - d] : 0;
        __syncthreads();
        pp[t] += a;
        __syncthreads();
    }
    bases[t * NBUCK + bkt] = gbase[bkt] + pp[t] - v;   // exclusive prefix over blocks
}

// ---------- 4. scatter with precomputed bases (no reservation atomics) ----------
__global__ void k_scatter2(const int* __restrict__ src, const int* __restrict__ dst,
                           const int* __restrict__ basesA, const int* __restrict__ basesB,
                           uint2* __restrict__ pairs, int* __restrict__ keysB, int E) {
    __shared__ int lcA[NBUCK], lcB[NBUCK];
    int t = threadIdx.x, blk = blockIdx.x;
    for (int j = t; j < NBUCK; j += 256) {
        lcA[j] = basesA[blk * NBUCK + j];
        lcB[j] = basesB[blk * NBUCK + j];
    }
    __syncthreads();
    int lo = blk * CHUNK, hi = min(lo + CHUNK, E);
    for (int i = lo + t; i < hi; i += 256) {
        int s = src[i], d = dst[i];
        int pA = atomicAdd(&lcA[d / BSZ], 1);
        pairs[pA] = make_uint2((unsigned)s, (unsigned)d);
        int pB = atomicAdd(&lcB[s / BSZ], 1);
        keysB[pB] = s;
    }
}

// ---------- 5. fused CSR finalize + in-LDS segment sort + src count ----------
// one 1024-thread block per bucket; esrc staged/sorted in LDS (global fallback)
__global__ void k_csr2(const uint2* __restrict__ pairs, const int* __restrict__ keysBsrc,
                       const int* __restrict__ gbaseA, const int* __restrict__ gbaseB,
                       int* __restrict__ offsets, float* __restrict__ in_norm,
                       float* __restrict__ out_norm, int* __restrict__ esrc) {
    extern __shared__ int esrc_s[];           // CAP ints (dynamic, 40 KB)
    __shared__ int hist[256], scn[256], curs[256];
    int b = blockIdx.x, t = threadIdx.x;
    int node0 = b * BSZ;
    int bstart = gbaseA[b], bend = gbaseA[b + 1], sz = bend - bstart;
    bool useLds = (sz <= CAP);
    int* seg = useLds ? esrc_s : (esrc + bstart);   // generic pointer: LDS or global
    if (t < 256) hist[t] = 0;
    __syncthreads();
    for (int i = bstart + t; i < bend; i += 1024)
        atomicAdd(&hist[(int)pairs[i].y - node0], 1);
    __syncthreads();
    if (t < 256) scn[t] = hist[t];
    __syncthreads();
    for (int d = 1; d < 256; d <<= 1) {
        int v = (t < 256 && t >= d) ? scn[t - d] : 0;
        __syncthreads();
        if (t < 256) scn[t] += v;
        __syncthreads();
    }
    if (t < BSZ) {
        int excl = scn[t] - hist[t];
        offsets[node0 + t] = bstart + excl;
        in_norm[node0 + t] = rsqrtf((float)max(hist[t], 1));
        curs[t] = excl;
    }
    __syncthreads();
    for (int i = bstart + t; i < bend; i += 1024) {
        uint2 p = pairs[i];
        int l = atomicAdd(&curs[(int)p.y - node0], 1);
        seg[l] = (int)p.x;
    }
    __syncthreads();
    // per-node bitonic sort (verified R6 network); wave w handles nodes w, w+16, ...
    {
        int wv = t >> 6, lane = t & 63;
        const int INF = 0x7FFFFFFF;
        for (int n = wv; n < BSZ; n += 16) {
            int len = hist[n];
            if (len <= 1) continue;
            int lo = scn[n] - hist[n];
            int v0 = (lane < len) ? seg[lo + lane] : INF;
            int v1 = (64 + lane < len) ? seg[lo + 64 + lane] : INF;
#pragma unroll
            for (int k = 2; k <= 128; k <<= 1) {
#pragma unroll
                for (int d = 64; d > 0; d >>= 1) {
                    if (d >= k) continue;
                    if (d == 64) {
                        int a = min(v0, v1), bb = max(v0, v1);
                        v0 = a; v1 = bb;
                    } else {
                        int w0 = __shfl_xor(v0, d, 64);
                        int w1 = __shfl_xor(v1, d, 64);
                        bool up0 = ((lane & k) == 0);
                        bool up1 = (((64 + lane) & k) == 0);
                        bool lower = ((lane & d) == 0);
                        v0 = (lower == up0) ? min(v0, w0) : max(v0, w0);
                        v1 = (lower == up1) ? min(v1, w1) : max(v1, w1);
                    }
                }
            }
            if (lane < len) seg[lo + lane] = v0;
            if (64 + lane < len) seg[lo + 64 + lane] = v1;
        }
    }
    __syncthreads();
    if (useLds) {
        for (int i = t; i < sz; i += 1024) esrc[bstart + i] = esrc_s[i];
    }
    if (t < 256) hist[t] = 0;
    __syncthreads();
    // phase B: src counts -> out_norm (same bucket index over keysB)
    int kb0 = gbaseB[b], kb1 = gbaseB[b + 1];
    for (int i = kb0 + t; i < kb1; i += 1024)
        atomicAdd(&hist[keysBsrc[i] - node0], 1);
    __syncthreads();
    if (t < BSZ) out_norm[node0 + t] = rsqrtf((float)max(hist[t], 1));
}

// ---------- 6. xs = bf16(x * out_norm), fp32 -> bf16 ----------
__global__ void k_scale(const float4* __restrict__ x4, const float* __restrict__ out_norm,
                        uint2* __restrict__ xs, int total4) {
    int i = blockIdx.x * blockDim.x + threadIdx.x;
    if (i < total4) {
        int node = i >> 5;                 // 32 float4 per node
        float on = out_norm[node];
        float4 v = x4[i];
        uint2 o;
        o.x = pack2(v.x * on, v.y * on);
        o.y = pack2(v.z * on, v.w * on);
        xs[i] = o;
    }
}

// ---------- 7. aggregate (R8-verified): 4x unrolled gather ----------
__global__ void k_aggregate(const int* __restrict__ offsets, const int* __restrict__ esrc,
                            const uint4* __restrict__ feat, const float* __restrict__ in_norm,
                            uint4* __restrict__ out, int N) {
    int node = blockIdx.x * 4 + (threadIdx.x >> 6);
    if (node >= N) return;
    int lane = threadIdx.x & 63;
    int g = lane >> 4;      // edge subgroup
    int c = lane & 15;      // 16B chunk within 256B row
    int lo = offsets[node], hi = offsets[node + 1];
    float a0 = 0.f, a1 = 0.f, a2 = 0.f, a3 = 0.f, a4 = 0.f, a5 = 0.f, a6 = 0.f, a7 = 0.f;
    int k = lo + g;
    for (; k + 12 < hi; k += 16) {
        int s0 = esrc[k];
        int s1 = esrc[k + 4];
        int s2 = esrc[k + 8];
        int s3 = esrc[k + 12];
        uint4 p0 = feat[(size_t)s0 * 16 + c];
        uint4 p1 = feat[(size_t)s1 * 16 + c];
        uint4 p2 = feat[(size_t)s2 * 16 + c];
        uint4 p3 = feat[(size_t)s3 * 16 + c];
        a0 += b2f_lo(p0.x); a1 += b2f_hi(p0.x);
        a2 += b2f_lo(p0.y); a3 += b2f_hi(p0.y);
        a4 += b2f_lo(p0.z); a5 += b2f_hi(p0.z);
        a6 += b2f_lo(p0.w); a7 += b2f_hi(p0.w);
        a0 += b2f_lo(p1.x); a1 += b2f_hi(p1.x);
        a2 += b2f_lo(p1.y); a3 += b2f_hi(p1.y);
        a4 += b2f_lo(p1.z); a5 += b2f_hi(p1.z);
        a6 += b2f_lo(p1.w); a7 += b2f_hi(p1.w);
        a0 += b2f_lo(p2.x); a1 += b2f_hi(p2.x);
        a2 += b2f_lo(p2.y); a3 += b2f_hi(p2.y);
        a4 += b2f_lo(p2.z); a5 += b2f_hi(p2.z);
        a6 += b2f_lo(p2.w); a7 += b2f_hi(p2.w);
        a0 += b2f_lo(p3.x); a1 += b2f_hi(p3.x);
        a2 += b2f_lo(p3.y); a3 += b2f_hi(p3.y);
        a4 += b2f_lo(p3.z); a5 += b2f_hi(p3.z);
        a6 += b2f_lo(p3.w); a7 += b2f_hi(p3.w);
    }
    for (; k < hi; k += 4) {
        int s = esrc[k];
        uint4 p = feat[(size_t)s * 16 + c];
        a0 += b2f_lo(p.x); a1 += b2f_hi(p.x);
        a2 += b2f_lo(p.y); a3 += b2f_hi(p.y);
        a4 += b2f_lo(p.z); a5 += b2f_hi(p.z);
        a6 += b2f_lo(p.w); a7 += b2f_hi(p.w);
    }
    a0 += __shfl_xor(a0, 16, 64); a0 += __shfl_xor(a0, 32, 64);
    a1 += __shfl_xor(a1, 16, 64); a1 += __shfl_xor(a1, 32, 64);
    a2 += __shfl_xor(a2, 16, 64); a2 += __shfl_xor(a2, 32, 64);
    a3 += __shfl_xor(a3, 16, 64); a3 += __shfl_xor(a3, 32, 64);
    a4 += __shfl_xor(a4, 16, 64); a4 += __shfl_xor(a4, 32, 64);
    a5 += __shfl_xor(a5, 16, 64); a5 += __shfl_xor(a5, 32, 64);
    a6 += __shfl_xor(a6, 16, 64); a6 += __shfl_xor(a6, 32, 64);
    a7 += __shfl_xor(a7, 16, 64); a7 += __shfl_xor(a7, 32, 64);
    if (g == 0) {
        float inn = in_norm[node];
        uint4 o;
        o.x = pack2(a0 * inn, a1 * inn);
        o.y = pack2(a2 * inn, a3 * inn);
        o.z = pack2(a4 * inn, a5 * inn);
        o.w = pack2(a6 * inn, a7 * inn);
        out[(size_t)node * 16 + c] = o;
    }
}

// ---------- 8. weight transpose + bf16 cast ----------
__global__ void k_transpose(const float* __restrict__ w, unsigned short* __restrict__ wt,
                            int K, int N) {
    int i = blockIdx.x * blockDim.x + threadIdx.x;
    if (i < K * N) {
        int k = i / N, n = i - k * N;
        wt[(size_t)n * K + k] = f2b(w[i]);
    }
}

// ---------- 9. MFMA GEMM (conv layers) ----------
__global__ void k_gemm(const unsigned short* __restrict__ A, const unsigned short* __restrict__ WT,
                       const float* __restrict__ bias, const float* __restrict__ row_scale,
                       unsigned short* __restrict__ C, int M, int N, int K) {
    int wv = threadIdx.x >> 6, lane = threadIdx.x & 63;
    int m = lane & 15, q = lane >> 4;
    int row0 = blockIdx.x * 32;
    int col0 = blockIdx.y * 64 + wv * 16;
    const unsigned short* a0 = A + (size_t)(row0 + m) * K + q * 8;
    const unsigned short* a1 = a0 + (size_t)16 * K;
    const unsigned short* bp = WT + (size_t)(col0 + m) * K + q * 8;
    f32x4 acc0 = {0.f, 0.f, 0.f, 0.f};
    f32x4 acc1 = {0.f, 0.f, 0.f, 0.f};
    for (int k = 0; k < K; k += 32) {
        bf16x8 bfr = *(const bf16x8*)(bp + k);
        bf16x8 af0 = *(const bf16x8*)(a0 + k);
        bf16x8 af1 = *(const bf16x8*)(a1 + k);
        acc0 = __builtin_amdgcn_mfma_f32_16x16x32_bf16(af0, bfr, acc0, 0, 0, 0);
        acc1 = __builtin_amdgcn_mfma_f32_16x16x32_bf16(af1, bfr, acc1, 0, 0, 0);
    }
    int c = col0 + m;
    float bc = bias[c];
#pragma unroll
    for (int r = 0; r < 4; r++) {
        int rr = row0 + q * 4 + r;
        float v = fmaxf(acc0[r] + bc, 0.f);
        if (row_scale) v *= row_scale[rr];
        C[(size_t)rr * N + c] = f2b(v);
        int rr1 = rr + 16;
        float v1 = fmaxf(acc1[r] + bc, 0.f);
        if (row_scale) v1 *= row_scale[rr1];
        C[(size_t)rr1 * N + c] = f2b(v1);
    }
}

// ---------- 10. fused MLP ----------
__global__ void k_mlp(const unsigned short* __restrict__ A,
                      const unsigned short* __restrict__ WT1, const float* __restrict__ bm1,
                      const unsigned short* __restrict__ WT2, const float* __restrict__ bm2,
                      float* __restrict__ out, int M) {
    __shared__ unsigned short H[32][264];
    int wv = threadIdx.x >> 6, lane = threadIdx.x & 63;
    int m = lane & 15, q = lane >> 4;
    int row0 = blockIdx.x * 32;

    const unsigned short* a0p = A + (size_t)(row0 + m) * 128 + q * 8;
    const unsigned short* a1p = a0p + (size_t)16 * 128;
    bf16x8 af0[4], af1[4];
#pragma unroll
    for (int s = 0; s < 4; s++) {
        af0[s] = *(const bf16x8*)(a0p + s * 32);
        af1[s] = *(const bf16x8*)(a1p + s * 32);
    }
#pragma unroll
    for (int cb = 0; cb < 4; cb++) {
        int colh = cb * 64 + wv * 16 + m;
        const unsigned short* bp = WT1 + (size_t)colh * 128 + q * 8;
        f32x4 acc0 = {0.f, 0.f, 0.f, 0.f};
        f32x4 acc1 = {0.f, 0.f, 0.f, 0.f};
#pragma unroll
        for (int s = 0; s < 4; s++) {
            bf16x8 bfr = *(const bf16x8*)(bp + s * 32);
            acc0 = __builtin_amdgcn_mfma_f32_16x16x32_bf16(af0[s], bfr, acc0, 0, 0, 0);
            acc1 = __builtin_amdgcn_mfma_f32_16x16x32_bf16(af1[s], bfr, acc1, 0, 0, 0);
        }
        float bc = bm1[colh];
#pragma unroll
        for (int r = 0; r < 4; r++) {
            H[q * 4 + r][colh]      = f2b(fmaxf(acc0[r] + bc, 0.f));
            H[q * 4 + r + 16][colh] = f2b(fmaxf(acc1[r] + bc, 0.f));
        }
    }
    __syncthreads();

    int colo = wv * 16 + m;
    const unsigned short* bp2 = WT2 + (size_t)colo * 256 + q * 8;
    f32x4 acc0 = {0.f, 0.f, 0.f, 0.f};
    f32x4 acc1 = {0.f, 0.f, 0.f, 0.f};
#pragma unroll
    for (int s = 0; s < 8; s++) {
        bf16x8 bfr  = *(const bf16x8*)(bp2 + s * 32);
        bf16x8 ha0  = *(const bf16x8*)(&H[m][s * 32 + q * 8]);
        bf16x8 ha1  = *(const bf16x8*)(&H[m + 16][s * 32 + q * 8]);
        acc0 = __builtin_amdgcn_mfma_f32_16x16x32_bf16(ha0, bfr, acc0, 0, 0, 0);
        acc1 = __builtin_amdgcn_mfma_f32_16x16x32_bf16(ha1, bfr, acc1, 0, 0, 0);
    }
    float bc = bm2[colo];
#pragma unroll
    for (int r = 0; r < 4; r++) {
        out[(size_t)(row0 + q * 4 + r) * 64 + colo]      = acc0[r] + bc;
        out[(size_t)(row0 + q * 4 + r + 16) * 64 + colo] = acc1[r] + bc;
    }
}

extern "C" void kernel_launch(void* const* d_in, const int* in_sizes, int n_in,
                              void* d_out, int out_size, void* d_ws, size_t ws_size,
                              hipStream_t stream) {
    const float* x    = (const float*)d_in[0];
    const int*   src  = (const int*)d_in[1];
    const int*   dst  = (const int*)d_in[2];
    const float* w1   = (const float*)d_in[3];
    const float* b1   = (const float*)d_in[4];
    const float* w2   = (const float*)d_in[5];
    const float* b2   = (const float*)d_in[6];
    const float* wm1  = (const float*)d_in[7];
    const float* bm1  = (const float*)d_in[8];
    const float* wm2  = (const float*)d_in[9];
    const float* bm2  = (const float*)d_in[10];

    const int N = N_NODES;
    const int E = N_EDGES;

    char* p = (char*)d_ws;
    auto alloc = [&](size_t bytes) -> void* {
        void* r = (void*)p;
        p += (bytes + 255) & ~(size_t)255;
        return r;
    };
    int*   gcntA   = (int*)alloc((NBUCK + 8) * 4);
    int*   gcntB   = (int*)alloc((NBUCK + 8) * 4);
    int*   gbaseA  = (int*)alloc((NBUCK + 8) * 4);
    int*   gbaseB  = (int*)alloc((NBUCK + 8) * 4);
    int*   countsA = (int*)alloc((size_t)NBUCK * NSCAT * 4);
    int*   countsB = (int*)alloc((size_t)NBUCK * NSCAT * 4);
    int*   basesA  = (int*)alloc((size_t)NSCAT * NBUCK * 4);
    int*   basesB  = (int*)alloc((size_t)NSCAT * NBUCK * 4);
    int*   offsets = (int*)alloc((size_t)(N + 1) * 4);
    float* out_norm = (float*)alloc((size_t)N * 4);
    float* in_norm  = (float*)alloc((size_t)N * 4);
    int*   esrc     = (int*)alloc((size_t)E * 4);
    unsigned int* bufA = (unsigned int*)alloc((size_t)N * 128 * 2);  // xs, then agg2
    unsigned int* bufB = (unsigned int*)alloc((size_t)N * 128 * 2);  // pairs, agg1, h2
    unsigned int* bufC = (unsigned int*)alloc((size_t)N * 128 * 2);  // keysB, hs1
    unsigned short* wt1  = (unsigned short*)alloc(128 * 128 * 2);
    unsigned short* wt2  = (unsigned short*)alloc(128 * 128 * 2);
    unsigned short* wtm1 = (unsigned short*)alloc(256 * 128 * 2);
    unsigned short* wtm2 = (unsigned short*)alloc(64 * 256 * 2);
    (void)ws_size; (void)n_in; (void)in_sizes; (void)out_size;

    uint2* pairs = (uint2*)bufB;   // 25.6 MB, dead until agg1 output
    int*   keysB = (int*)bufC;     // 12.8 MB, dead until gemm1 output

    hipMemsetAsync(gcntA, 0, (NBUCK + 8) * 4, stream);
    hipMemsetAsync(gcntB, 0, (NBUCK + 8) * 4, stream);

    const int TB = 256;
    // CSR build: per-block hist -> bucket scan -> deterministic block bases ->
    // scatter -> fused csr+sort+count
    k_hist_pb<<<dim3(NSCAT), dim3(TB), 0, stream>>>(src, dst, countsA, countsB,
                                                    gcntA, gcntB, E);
    k_scan_coarse<<<dim3(1), dim3(512), 0, stream>>>(gcntA, gcntB, gbaseA, gbaseB, offsets);
    k_blockbase<<<dim3(2 * NBUCK), dim3(TB), 0, stream>>>(countsA, countsB,
                                                          gbaseA, gbaseB, basesA, basesB);
    k_scatter2<<<dim3(NSCAT), dim3(TB), 0, stream>>>(src, dst, basesA, basesB,
                                                     pairs, keysB, E);
    k_csr2<<<dim3(NBUCK), dim3(1024), CAP * 4, stream>>>(pairs, keysB, gbaseA, gbaseB,
                                                         offsets, in_norm, out_norm, esrc);

    // xs = bf16(x * out_norm)
    k_scale<<<dim3((N * 32 + TB - 1) / TB), dim3(TB), 0, stream>>>(
        (const float4*)x, out_norm, (uint2*)bufA, N * 32);
    // weight transposes (fp32 -> bf16)
    k_transpose<<<dim3((128 * 128 + TB - 1) / TB), dim3(TB), 0, stream>>>(w1, wt1, 128, 128);
    k_transpose<<<dim3((128 * 128 + TB - 1) / TB), dim3(TB), 0, stream>>>(w2, wt2, 128, 128);
    k_transpose<<<dim3((128 * 256 + TB - 1) / TB), dim3(TB), 0, stream>>>(wm1, wtm1, 128, 256);
    k_transpose<<<dim3((256 * 64 + TB - 1) / TB), dim3(TB), 0, stream>>>(wm2, wtm2, 256, 64);

    // conv1: aggregate (bufA -> bufB), gemm w1 + relu + fold out_norm (-> bufC)
    k_aggregate<<<dim3(N / 4), dim3(TB), 0, stream>>>(
        offsets, esrc, (const uint4*)bufA, in_norm, (uint4*)bufB, N);
    k_gemm<<<dim3(N / 32, 2), dim3(TB), 0, stream>>>(
        (const unsigned short*)bufB, wt1, b1, out_norm, (unsigned short*)bufC, N, 128, 128);

    // conv2: aggregate (bufC -> bufA), gemm w2 + relu (-> bufB)
    k_aggregate<<<dim3(N / 4), dim3(TB), 0, stream>>>(
        offsets, esrc, (const uint4*)bufC, in_norm, (uint4*)bufA, N);
    k_gemm<<<dim3(N / 32, 2), dim3(TB), 0, stream>>>(
        (const unsigned short*)bufA, wt2, b2, (const float*)nullptr, (unsigned short*)bufB, N, 128, 128);

    // fused MLP: bufB -> d_out (fp32)
    k_mlp<<<dim3(N / 32), dim3(TB), 0, stream>>>(
        (const unsigned short*)bufB, wtm1, bm1, wtm2, bm2, (float*)d_out, N);
}